// Round 13
// baseline (4901.996 us; speedup 1.0000x reference)
//
#include <hip/hip_runtime.h>
#include <cmath>

#define Bn 64
#define Tn 512
#define Dn 400
#define Ln 25
#define Hn 200
#define G4n 800
#define TCn 64
#define NCH 8
#define NPADn 832

// ---- workspace layout (float offsets); total ~86.7 MB ----
constexpr size_t OFF_WIHT = 0;                                   // [2][400][832] f32
constexpr size_t OFF_WHHP = OFF_WIHT + (size_t)2*Dn*NPADn;       // (unused, kept for layout stability)
constexpr size_t OFF_WPK  = OFF_WHHP + (size_t)2*Hn*G4n;         // [2][100(j2)][800(u)] uint (bf16 pair over j)
constexpr size_t OFF_BSUM = OFF_WPK + (size_t)2*100*G4n;         // [2][800]
constexpr size_t OFF_GB   = OFF_BSUM + (size_t)2*G4n;            // 2 slots x [2][64][64][800] bf16
constexpr size_t OFF_HCAT = OFF_GB + (size_t)2*2*Bn*TCn*G4n/2;   // [64][512][400] f32
constexpr size_t OFF_E    = OFF_HCAT + (size_t)Bn*Tn*2*Hn;       // [64][512][25]
constexpr size_t OFF_HST  = OFF_E + (size_t)Bn*Tn*Ln;            // [2][64][200]
constexpr size_t OFF_CST  = OFF_HST + (size_t)2*Bn*Hn;           // [2][64][200]
constexpr size_t OFF_PART = OFF_CST + (size_t)2*Bn*Hn;           // [64]

#define SMEM_BYTES 153664   // rec: 64000(WL)+1664(hbufF); gemm: 4x13056; emis: 40448+4x25856

__device__ __forceinline__ float sigf(float x) { return 1.0f / (1.0f + expf(-x)); }

// ---------------- prep: pack Whh as bf16 j-pairs [d][j2][u], transpose Wih, zero state ----------------
__global__ void prep_kernel(const float* __restrict__ Wih_f, const float* __restrict__ Whh_f,
                            const float* __restrict__ bih_f, const float* __restrict__ bhh_f,
                            const float* __restrict__ Wih_b, const float* __restrict__ Whh_b,
                            const float* __restrict__ bih_b, const float* __restrict__ bhh_b,
                            float* __restrict__ ws) {
    int tid = blockIdx.x * blockDim.x + threadIdx.x;
    int nth = gridDim.x * blockDim.x;
    float* WihT = ws + OFF_WIHT;
    unsigned int* WPK = (unsigned int*)(ws + OFF_WPK);
    float* bsum = ws + OFF_BSUM;
    float* hst  = ws + OFF_HST;
    float* cst  = ws + OFF_CST;
    for (int i = tid; i < 2*Dn*NPADn; i += nth) {
        int d = i / (Dn*NPADn); int r = i % (Dn*NPADn); int k = r / NPADn; int g = r % NPADn;
        const float* W = d ? Wih_b : Wih_f;
        WihT[i] = (g < G4n) ? W[(size_t)g*Dn + k] : 0.0f;
    }
    for (int i = tid; i < 2*100*G4n; i += nth) {   // WPK[d][j2][u]: lo=Whh[q*H+k][2j2], hi=[2j2+1]
        int d = i / (100*G4n); int r = i % (100*G4n);
        int j2 = r / G4n; int u = r % G4n;
        int k = u >> 2, q = u & 3;
        const float* W = d ? Whh_b : Whh_f;
        unsigned int lo = __float_as_uint(W[(size_t)(q*Hn + k)*Hn + 2*j2]) >> 16;
        unsigned int hi = __float_as_uint(W[(size_t)(q*Hn + k)*Hn + 2*j2 + 1]) & 0xffff0000u;
        WPK[i] = hi | lo;
    }
    for (int i = tid; i < 2*G4n; i += nth) {
        int d = i / G4n; int g = i % G4n;
        bsum[i] = d ? (bih_b[g] + bhh_b[g]) : (bih_f[g] + bhh_f[g]);
    }
    for (int i = tid; i < 2*Bn*Hn; i += nth) { hst[i] = 0.0f; cst[i] = 0.0f; }
}

// ---------------- gemm role: one 256-thread quarter computes one (g-tile, b-pair, dir) tile ----------------
__device__ __forceinline__ void gemm_role(const float* __restrict__ X, float* __restrict__ ws,
                                          int chunk, int tile, int tid, char* smem) {
    const float* WihT = ws + OFF_WIHT;
    const float* bsum = ws + OFF_BSUM;
    unsigned short* Gb = (unsigned short*)(ws + OFF_GB) + (size_t)(chunk & 1) * 2 * Bn * TCn * G4n;
    int q4 = tid >> 8;
    int t2 = tid & 255;
    float* As = (float*)(smem + q4 * 13056);        // [16][136]
    float* Bs = As + 16 * 136;                      // [16][68]
    int g0i = tile % 13; int rem = tile / 13;
    int bp = rem % 32;   int d = rem / 32;
    int g0 = g0i * 64;
    int tx = t2 % 16, ty = t2 / 16;
    int t_base = (d == 0) ? chunk * TCn : (Tn - (chunk + 1) * TCn);
    const float* Bmat = WihT + (size_t)d * Dn * NPADn;

    float acc[8][4] = {{0.f}};
    int lr = t2 / 2, lk = t2 % 2;
    int bk = t2 / 16, bg = t2 % 16;
    int a_b = bp * 2 + lr / 64;
    int a_t = t_base + (lr % 64);
    const float* Arow = X + ((size_t)a_b * Tn + a_t) * Dn;

    for (int kt = 0; kt < Dn; kt += 16) {
        float4 a4a = *(const float4*)(Arow + kt + lk * 8);
        float4 a4b = *(const float4*)(Arow + kt + lk * 8 + 4);
        float4 b4  = *(const float4*)(Bmat + (size_t)(kt + bk) * NPADn + g0 + bg * 4);
        __syncthreads();
        As[(lk*8+0)*136 + lr] = a4a.x; As[(lk*8+1)*136 + lr] = a4a.y;
        As[(lk*8+2)*136 + lr] = a4a.z; As[(lk*8+3)*136 + lr] = a4a.w;
        As[(lk*8+4)*136 + lr] = a4b.x; As[(lk*8+5)*136 + lr] = a4b.y;
        As[(lk*8+6)*136 + lr] = a4b.z; As[(lk*8+7)*136 + lr] = a4b.w;
        *(float4*)&Bs[bk*68 + bg*4] = b4;
        __syncthreads();
        #pragma unroll
        for (int kk = 0; kk < 16; ++kk) {
            float4 af0 = *(const float4*)&As[kk*136 + ty*8];
            float4 af1 = *(const float4*)&As[kk*136 + ty*8 + 4];
            float4 bf  = *(const float4*)&Bs[kk*68 + tx*4];
            acc[0][0] += af0.x*bf.x; acc[0][1] += af0.x*bf.y; acc[0][2] += af0.x*bf.z; acc[0][3] += af0.x*bf.w;
            acc[1][0] += af0.y*bf.x; acc[1][1] += af0.y*bf.y; acc[1][2] += af0.y*bf.z; acc[1][3] += af0.y*bf.w;
            acc[2][0] += af0.z*bf.x; acc[2][1] += af0.z*bf.y; acc[2][2] += af0.z*bf.z; acc[2][3] += af0.z*bf.w;
            acc[3][0] += af0.w*bf.x; acc[3][1] += af0.w*bf.y; acc[3][2] += af0.w*bf.z; acc[3][3] += af0.w*bf.w;
            acc[4][0] += af1.x*bf.x; acc[4][1] += af1.x*bf.y; acc[4][2] += af1.x*bf.z; acc[4][3] += af1.x*bf.w;
            acc[5][0] += af1.y*bf.x; acc[5][1] += af1.y*bf.y; acc[5][2] += af1.y*bf.z; acc[5][3] += af1.y*bf.w;
            acc[6][0] += af1.z*bf.x; acc[6][1] += af1.z*bf.y; acc[6][2] += af1.z*bf.z; acc[6][3] += af1.z*bf.w;
            acc[7][0] += af1.w*bf.x; acc[7][1] += af1.w*bf.y; acc[7][2] += af1.w*bf.z; acc[7][3] += af1.w*bf.w;
        }
    }
    #pragma unroll
    for (int ii = 0; ii < 8; ++ii) {
        int r = ty * 8 + ii;
        int b = bp * 2 + r / 64;
        int tloc = r % 64;
        #pragma unroll
        for (int jj = 0; jj < 4; ++jj) {
            int g = g0 + tx * 4 + jj;
            if (g < G4n) {
                int k = g % Hn, q = g / Hn;
                float v = acc[ii][jj] + bsum[d*G4n + g];
                Gb[(((size_t)d*Bn + b)*TCn + tloc)*G4n + k*4 + q] =
                    (unsigned short)(__float_as_uint(v) >> 16);
            }
        }
    }
}

// ---------------- rec role: per-thread gate component, bf16-packed weights, ONE barrier/step ----------------
// thread u in [0,800): component (k=u>>2, q=u&3); sums all 200 j in-thread.
// weights: j2 0..79 in 80 VGPR uints; j2 80..99 in LDS [20][800] (conflict-free).
__device__ __forceinline__ void rec_role(const float* __restrict__ mask, float* __restrict__ ws,
                                         int chunk, int b, int d, int tid, char* smem) {
    const unsigned short* Gbs = (const unsigned short*)(ws + OFF_GB) + (size_t)(chunk & 1) * 2 * Bn * TCn * G4n;
    float* Hcat = ws + OFF_HCAT;
    float* hst = ws + OFF_HST;
    float* cst = ws + OFF_CST;
    const unsigned int* WPK = (const unsigned int*)(ws + OFF_WPK);

    unsigned int* WL = (unsigned int*)smem;           // [20][800]  64000 B
    float* hbufF = (float*)(smem + 64000);            // [2][208]   1664 B

    int u = tid;
    bool act = (u < 800);
    int k = u >> 2, qq = u & 3;
    const unsigned int* WPKd = WPK + (size_t)d * 100 * G4n;

    // ---- VGPR tier: 80 packed uints (j2 = 0..79), named vars ----
    #define LWU(i) unsigned int wu##i = WPKd[(size_t)(i) * 800 + (u & 1023)];
    LWU(0) LWU(1) LWU(2) LWU(3) LWU(4) LWU(5) LWU(6) LWU(7) LWU(8) LWU(9)
    LWU(10) LWU(11) LWU(12) LWU(13) LWU(14) LWU(15) LWU(16) LWU(17) LWU(18) LWU(19)
    LWU(20) LWU(21) LWU(22) LWU(23) LWU(24) LWU(25) LWU(26) LWU(27) LWU(28) LWU(29)
    LWU(30) LWU(31) LWU(32) LWU(33) LWU(34) LWU(35) LWU(36) LWU(37) LWU(38) LWU(39)
    LWU(40) LWU(41) LWU(42) LWU(43) LWU(44) LWU(45) LWU(46) LWU(47) LWU(48) LWU(49)
    LWU(50) LWU(51) LWU(52) LWU(53) LWU(54) LWU(55) LWU(56) LWU(57) LWU(58) LWU(59)
    LWU(60) LWU(61) LWU(62) LWU(63) LWU(64) LWU(65) LWU(66) LWU(67) LWU(68) LWU(69)
    LWU(70) LWU(71) LWU(72) LWU(73) LWU(74) LWU(75) LWU(76) LWU(77) LWU(78) LWU(79)
    #undef LWU
    // ---- LDS tier: stage j2 = 80..99 ----
    if (act) {
        #pragma unroll
        for (int jj = 0; jj < 20; ++jj)
            WL[jj * 800 + u] = WPKd[(size_t)(80 + jj) * 800 + u];
    }
    size_t soff = ((size_t)d * Bn + b) * Hn;
    float hr = 0.f, cr = 0.f;
    if (act && qq == 0) {
        hr = hst[soff + k];
        cr = cst[soff + k];
    }
    if (tid < 200) hbufF[tid] = hst[soff + tid];
    __syncthreads();

    const unsigned short* GbRow = Gbs + ((size_t)d * Bn + b) * TCn * G4n;
    const float* mrow = mask + (size_t)b * Tn;
    float* Hrow = Hcat + (size_t)b * Tn * (2 * Hn) + d * Hn;

    #define UNL(W) __uint_as_float((W) << 16)
    #define UNH(W) __uint_as_float((W) & 0xffff0000u)
    #define GRP(g, WA, WB) { float4 h4v = hf4[g]; \
        a0 += UNL(WA) * h4v.x; a1 += UNH(WA) * h4v.y; \
        a2 += UNL(WB) * h4v.z; a3 += UNH(WB) * h4v.w; }
    #define GRPL(g, I0, I1) { unsigned int wa = WL[(I0)*800 + u], wb = WL[(I1)*800 + u]; \
        float4 h4v = hf4[g]; \
        a0 += UNL(wa) * h4v.x; a1 += UNH(wa) * h4v.y; \
        a2 += UNL(wb) * h4v.z; a3 += UNH(wb) * h4v.w; }

    int cur = 0;
    for (int s = 0; s < TCn; ++s) {
        int tg, tloc;
        if (d == 0) { tloc = s; tg = chunk * TCn + s; }
        else        { tloc = TCn - 1 - s; tg = Tn - 1 - (chunk * TCn + s); }
        // deferred coalesced Hcat store of previous step's h
        if (s > 0 && tid < 200) {
            int tgp = (d == 0) ? (chunk * TCn + s - 1) : (Tn - 1 - (chunk * TCn + s - 1));
            Hrow[(size_t)tgp * (2 * Hn) + tid] = hbufF[cur * 208 + tid];
        }
        if (act) {
            // prefetch gate-input (bf16) + mask
            float m_ = mrow[tg];
            unsigned short gub = GbRow[(size_t)tloc * G4n + u];
            float gq = __uint_as_float((unsigned int)gub << 16);
            // gemv over all 200 j (50 groups of 4)
            const float4* hf4 = (const float4*)(hbufF + cur * 208);
            float a0 = gq, a1 = 0.f, a2 = 0.f, a3 = 0.f;
            GRP(0,wu0,wu1)   GRP(1,wu2,wu3)   GRP(2,wu4,wu5)   GRP(3,wu6,wu7)
            GRP(4,wu8,wu9)   GRP(5,wu10,wu11) GRP(6,wu12,wu13) GRP(7,wu14,wu15)
            GRP(8,wu16,wu17) GRP(9,wu18,wu19) GRP(10,wu20,wu21) GRP(11,wu22,wu23)
            GRP(12,wu24,wu25) GRP(13,wu26,wu27) GRP(14,wu28,wu29) GRP(15,wu30,wu31)
            GRP(16,wu32,wu33) GRP(17,wu34,wu35) GRP(18,wu36,wu37) GRP(19,wu38,wu39)
            GRP(20,wu40,wu41) GRP(21,wu42,wu43) GRP(22,wu44,wu45) GRP(23,wu46,wu47)
            GRP(24,wu48,wu49) GRP(25,wu50,wu51) GRP(26,wu52,wu53) GRP(27,wu54,wu55)
            GRP(28,wu56,wu57) GRP(29,wu58,wu59) GRP(30,wu60,wu61) GRP(31,wu62,wu63)
            GRP(32,wu64,wu65) GRP(33,wu66,wu67) GRP(34,wu68,wu69) GRP(35,wu70,wu71)
            GRP(36,wu72,wu73) GRP(37,wu74,wu75) GRP(38,wu76,wu77) GRP(39,wu78,wu79)
            GRPL(40,0,1)  GRPL(41,2,3)  GRPL(42,4,5)  GRPL(43,6,7)  GRPL(44,8,9)
            GRPL(45,10,11) GRPL(46,12,13) GRPL(47,14,15) GRPL(48,16,17) GRPL(49,18,19)
            float g = (a0 + a1) + (a2 + a3);
            // one activation per thread; quad gather via DPP shuffles
            float arg = (qq == 2) ? 2.f * g : g;
            float sg = 1.f / (1.f + expf(-arg));
            float a = (qq == 2) ? 2.f * sg - 1.f : sg;   // tanh(g) = 2*sig(2g)-1
            float x1 = __shfl_xor(a, 1);
            float x2 = __shfl_xor(a, 2);
            float x3 = __shfl_xor(x1, 2);
            if (qq == 0) {
                float i_ = a, f_ = x1, gg_ = x2, o_ = x3;
                float cn = f_ * cr + i_ * gg_;
                float hn = o_ * tanhf(cn);
                cr = m_ * cn + (1.f - m_) * cr;
                hr = m_ * hn + (1.f - m_) * hr;
                hbufF[(cur ^ 1) * 208 + k] = hr;
            }
        }
        __syncthreads();
        cur ^= 1;
    }
    #undef GRP
    #undef GRPL
    #undef UNL
    #undef UNH
    if (tid < 200) {
        int tgp = (d == 0) ? (chunk * TCn + TCn - 1) : (Tn - 1 - (chunk * TCn + TCn - 1));
        Hrow[(size_t)tgp * (2 * Hn) + tid] = hbufF[cur * 208 + tid];
    }
    if (act && qq == 0) {
        hst[soff + k] = hr;
        cst[soff + k] = cr;
    }
}

// ---------------- emis role: quarter = 128 rows of E for rows t in [64,448) ----------------
__device__ __forceinline__ void emis_role(const float* __restrict__ mask,
                                          const float* __restrict__ Wl, const float* __restrict__ bl,
                                          float* __restrict__ ws, int blk, int tid, char* smem) {
    const float* Hcat = ws + OFF_HCAT;
    float* E = ws + OFF_E;
    float* Wls = (float*)smem;                        // 40400 B
    int q4 = tid >> 8, t2 = tid & 255;
    float* Hs = (float*)(smem + 40448 + q4 * 25856);  // 16*404 floats per quarter
    for (int i = tid; i < Ln * 100; i += 1024) {
        int l = i / 100, k4 = i % 100;
        *(float4*)&Wls[l*404 + k4*4] = *(const float4*)(Wl + (size_t)l*Dn + k4*4);
    }
    int Q = blk * 4 + q4;            // 0..191
    int b = Q / 3, seg = Q % 3;
    int rbase = b * Tn + 64 + seg * 128;
    for (int sub = 0; sub < 8; ++sub) {
        int r0 = rbase + sub * 16;
        __syncthreads();
        for (int i = t2; i < 16 * 100; i += 256) {
            int r = i / 100, k4 = i % 100;
            *(float4*)&Hs[r*404 + k4*4] = *(const float4*)(Hcat + (size_t)(r0 + r)*Dn + k4*4);
        }
        __syncthreads();
        for (int o = t2; o < 16 * Ln; o += 256) {
            int r = o / Ln, l = o % Ln;
            float acc = 0.f;
            #pragma unroll 4
            for (int k4 = 0; k4 < 100; ++k4) {
                float4 h = *(const float4*)&Hs[r*404 + k4*4];
                float4 wv = *(const float4*)&Wls[l*404 + k4*4];
                acc += h.x*wv.x + h.y*wv.y + h.z*wv.z + h.w*wv.w;
            }
            int row = r0 + r;
            float m = mask[row];
            E[(size_t)row * Ln + l] = (acc + bl[l]) * m;
        }
    }
}

// ---------------- fused launch: [0,nrec)=rec; [nrec,nrec+ngemm)=gemm; rest=emis ----------------
__global__ __launch_bounds__(1024, 4) void fused_kernel(const float* __restrict__ X,
                                                        const float* __restrict__ mask,
                                                        const float* __restrict__ Wl,
                                                        const float* __restrict__ bl,
                                                        float* __restrict__ ws,
                                                        int rec_chunk, int gemm_chunk,
                                                        int nrec, int ngemm) {
    __shared__ __align__(16) char smem[SMEM_BYTES];
    int bx = blockIdx.x;
    int tid = threadIdx.x;
    if (bx < nrec) {
        rec_role(mask, ws, rec_chunk, bx & 63, bx >> 6, tid, smem);
    } else if (bx < nrec + ngemm) {
        int tile = (bx - nrec) * 4 + (tid >> 8);
        gemm_role(X, ws, gemm_chunk, tile, tid, smem);
    } else {
        emis_role(mask, Wl, bl, ws, bx - nrec - ngemm, tid, smem);
    }
}

// ---------------- emis2: edge rows t in [0,64) u [448,512) ----------------
__global__ __launch_bounds__(256) void emis2_kernel(const float* __restrict__ mask,
                                                    const float* __restrict__ Wl,
                                                    const float* __restrict__ bl,
                                                    float* __restrict__ ws) {
    const float* Hcat = ws + OFF_HCAT;
    float* E = ws + OFF_E;
    __shared__ float Wls[Ln * 404];
    __shared__ float Hs[16 * 404];
    int tid = threadIdx.x;
    int b = blockIdx.x;
    for (int i = tid; i < Ln * 100; i += 256) {
        int l = i / 100, k4 = i % 100;
        *(float4*)&Wls[l*404 + k4*4] = *(const float4*)(Wl + (size_t)l*Dn + k4*4);
    }
    for (int sub = 0; sub < 8; ++sub) {
        int t0 = (sub < 4) ? sub * 16 : 448 + (sub - 4) * 16;
        int r0 = b * Tn + t0;
        __syncthreads();
        for (int i = tid; i < 16 * 100; i += 256) {
            int r = i / 100, k4 = i % 100;
            *(float4*)&Hs[r*404 + k4*4] = *(const float4*)(Hcat + (size_t)(r0 + r)*Dn + k4*4);
        }
        __syncthreads();
        for (int o = tid; o < 16 * Ln; o += 256) {
            int r = o / Ln, l = o % Ln;
            float acc = 0.f;
            #pragma unroll 4
            for (int k4 = 0; k4 < 100; ++k4) {
                float4 h = *(const float4*)&Hs[r*404 + k4*4];
                float4 wv = *(const float4*)&Wls[l*404 + k4*4];
                acc += h.x*wv.x + h.y*wv.y + h.z*wv.z + h.w*wv.w;
            }
            int row = r0 + r;
            float m = mask[row];
            E[(size_t)row * Ln + l] = (acc + bl[l]) * m;
        }
    }
}

// ---------------- fused CRF + Viterbi: 64 blocks x 128 threads; split-j across lane halves ----------------
__global__ __launch_bounds__(128) void decode_kernel(const float* __restrict__ mask,
                                                     const int* __restrict__ labels,
                                                     const float* __restrict__ trans,
                                                     const float* __restrict__ start,
                                                     const float* __restrict__ endv,
                                                     float* __restrict__ ws,
                                                     float* __restrict__ out) {
    int b = blockIdx.x;
    int tid = threadIdx.x;
    int wvid = tid >> 6;
    int ln = tid & 63;
    int half = (ln >> 5) & 1;
    int l = ln & 31;
    bool actl = (l < Ln);
    int jbase = half ? 13 : 0;
    int jcnt  = half ? 12 : 13;
    const float* E = ws + OFF_E;
    float* part = ws + OFF_PART;

    __shared__ __align__(16) float Es[Tn * Ln];
    __shared__ float trs[Ln * Ln];
    __shared__ unsigned char ptrs[Tn][Ln];
    __shared__ unsigned char ys[Tn];

    {
        const float4* src = (const float4*)(E + (size_t)b * Tn * Ln);
        float4* dst = (float4*)Es;
        for (int i = tid; i < Tn * Ln / 4; i += 128) dst[i] = src[i];
        for (int i = tid; i < Ln * Ln; i += 128) trs[i] = trans[i];
    }
    float cnt = 0.f;
    for (int t = ln; t < Tn; t += 64) cnt += mask[(size_t)b * Tn + t];
    for (int off = 32; off; off >>= 1) cnt += __shfl_xor(cnt, off);
    int len = (int)(cnt + 0.5f);
    float trc[13];
    #pragma unroll
    for (int j = 0; j < 13; ++j) trc[j] = -1e30f;
    if (actl) {
        for (int j = 0; j < jcnt; ++j) trc[j] = trans[(jbase + j) * Ln + l];
    }
    __syncthreads();

    if (wvid == 0) {
        // ---- CRF forward ----
        float alpha = actl ? start[l] + Es[l] : -1e30f;
        for (int t = 1; t < len; ++t) {
            float v[13];
            #pragma unroll
            for (int j = 0; j < 13; ++j) v[j] = __shfl(alpha, jbase + j) + trc[j];
            float a0 = fmaxf(v[0], v[1]), a1 = fmaxf(v[2], v[3]), a2 = fmaxf(v[4], v[5]);
            float a3 = fmaxf(v[6], v[7]), a4 = fmaxf(v[8], v[9]), a5 = fmaxf(v[10], v[11]);
            a0 = fmaxf(a0, a1); a2 = fmaxf(a2, a3); a4 = fmaxf(a4, a5);
            a0 = fmaxf(a0, a2); a4 = fmaxf(a4, v[12]);
            float m = fmaxf(a0, a4);
            float e[13];
            #pragma unroll
            for (int j = 0; j < 13; ++j) e[j] = __expf(v[j] - m);
            float s0 = (e[0] + e[1]) + (e[2] + e[3]);
            float s1 = (e[4] + e[5]) + (e[6] + e[7]);
            float s2 = (e[8] + e[9]) + (e[10] + e[11]);
            float s = ((s0 + s1) + (s2 + e[12]));
            float pm = __shfl_xor(m, 32);
            float ps = __shfl_xor(s, 32);
            float M = fmaxf(m, pm);
            float S = s * __expf(m - M) + ps * __expf(pm - M);
            float nv = M + __logf(S) + Es[t * Ln + l];
            alpha = actl ? nv : -1e30f;
        }
        float vfin = (ln < Ln) ? alpha + endv[l] : -1e30f;
        float mxf = vfin;
        for (int off = 32; off; off >>= 1) mxf = fmaxf(mxf, __shfl_xor(mxf, off));
        float sf = (ln < Ln) ? __expf(vfin - mxf) : 0.f;
        for (int off = 32; off; off >>= 1) sf += __shfl_xor(sf, off);
        float logZ = mxf + __logf(sf);
        float psum = 0.f;
        for (int t = ln; t < len; t += 64) {
            if (t >= 1) {
                int lt = labels[(size_t)b * Tn + t];
                int lp = labels[(size_t)b * Tn + t - 1];
                psum += Es[t * Ln + lt] + trs[lp * Ln + lt];
            }
        }
        for (int off = 32; off; off >>= 1) psum += __shfl_xor(psum, off);
        if (ln == 0) {
            int l0 = labels[(size_t)b * Tn];
            int yl = labels[(size_t)b * Tn + len - 1];
            part[b] = start[l0] + Es[l0] + psum + endv[yl] - logZ;
        }
    } else {
        // ---- Viterbi ----
        float delta = actl ? start[l] + Es[l] : -1e30f;
        for (int t = 1; t < len; ++t) {
            float best = -1e30f; int ba = 0;
            #pragma unroll
            for (int j = 0; j < 13; ++j) {
                float c = __shfl(delta, jbase + j) + trc[j];
                if (c > best) { best = c; ba = jbase + j; }
            }
            float pb = __shfl_xor(best, 32);
            int   pa = __shfl_xor(ba, 32);
            float b0 = half ? pb : best; int a0 = half ? pa : ba;
            float b1 = half ? best : pb; int a1 = half ? ba : pa;
            int   A  = (b1 > b0) ? a1 : a0;   // tie -> half0 (lower j) = jnp.argmax first-max
            float B  = fmaxf(b0, b1);
            float nd = B + Es[t * Ln + l];
            if (actl && half == 0) ptrs[t][l] = (unsigned char)A;
            delta = actl ? nd : -1e30f;
        }
        float bb = -1e30f; int y = 0;
        for (int j = 0; j < Ln; ++j) {
            float c = __shfl(delta, j) + endv[j];
            if (c > bb) { bb = c; y = j; }
        }
        if (ln == 0) {
            ys[len - 1] = (unsigned char)y;
            int yy = y;
            for (int t = len - 1; t >= 1; --t) { yy = ptrs[t][yy]; ys[t - 1] = (unsigned char)yy; }
        }
        __builtin_amdgcn_s_barrier();
        for (int t = ln; t < Tn; t += 64) {
            out[1 + (size_t)b * Tn + t] = (t < len) ? (float)ys[t] : 0.f;
        }
    }
}

// ---------------- finalize loss ----------------
__global__ __launch_bounds__(64) void fin_kernel(float* __restrict__ ws, float* __restrict__ out) {
    const float* part = ws + OFF_PART;
    int l = threadIdx.x;
    float v = (l < Bn) ? part[l] : 0.f;
    for (int off = 32; off; off >>= 1) v += __shfl_xor(v, off);
    if (l == 0) out[0] = -v / (float)Bn;
}

extern "C" void kernel_launch(void* const* d_in, const int* in_sizes, int n_in,
                              void* d_out, int out_size, void* d_ws, size_t ws_size,
                              hipStream_t stream) {
    (void)in_sizes; (void)n_in; (void)out_size; (void)ws_size;
    const float* X      = (const float*)d_in[0];
    const float* mask   = (const float*)d_in[1];
    const int*   labels = (const int*)d_in[2];
    const float* Wih_f  = (const float*)d_in[3];
    const float* Whh_f  = (const float*)d_in[4];
    const float* bih_f  = (const float*)d_in[5];
    const float* bhh_f  = (const float*)d_in[6];
    const float* Wih_b  = (const float*)d_in[7];
    const float* Whh_b  = (const float*)d_in[8];
    const float* bih_b  = (const float*)d_in[9];
    const float* bhh_b  = (const float*)d_in[10];
    const float* Wl     = (const float*)d_in[11];
    const float* bl     = (const float*)d_in[12];
    const float* trans  = (const float*)d_in[13];
    const float* start  = (const float*)d_in[14];
    const float* endv   = (const float*)d_in[15];
    float* ws  = (float*)d_ws;
    float* out = (float*)d_out;

    prep_kernel<<<128, 256, 0, stream>>>(Wih_f, Whh_f, bih_f, bhh_f,
                                         Wih_b, Whh_b, bih_b, bhh_b, ws);
    // L0: gemm chunk 0 only
    fused_kernel<<<208, 1024, 0, stream>>>(X, mask, Wl, bl, ws, 0, 0, 0, 208);
    // L1..L7: rec(c-1) overlapped with gemm(c)
    for (int c = 1; c < NCH; ++c)
        fused_kernel<<<336, 1024, 0, stream>>>(X, mask, Wl, bl, ws, c - 1, c, 128, 208);
    // L8: rec chunk 7 + emis for rows t in [64,448)
    fused_kernel<<<176, 1024, 0, stream>>>(X, mask, Wl, bl, ws, NCH - 1, 0, 128, 0);
    emis2_kernel<<<64, 256, 0, stream>>>(mask, Wl, bl, ws);
    decode_kernel<<<64, 128, 0, stream>>>(mask, labels, trans, start, endv, ws, out);
    fin_kernel<<<1, 64, 0, stream>>>(ws, out);
}

// Round 14
// 2122.975 us; speedup vs baseline: 2.3090x; 2.3090x over previous
//
#include <hip/hip_runtime.h>
#include <cmath>

#define Bn 64
#define Tn 512
#define Dn 400
#define Ln 25
#define Hn 200
#define G4n 800
#define TCn 64
#define NCH 8
#define NPADn 832
// Whh residency per thread (40 j-quads): 20 fp32 in VGPR, 17 bf16 in LDS, 3 bf16 streamed (L1-resident).
#define JV 20
#define JLB 17
#define JSB 3

// ---- workspace layout (float offsets); total ~86.7 MB ----
constexpr size_t OFF_WIHT = 0;                                   // [2][400][832] f32
constexpr size_t OFF_WHHP = OFF_WIHT + (size_t)2*Dn*NPADn;       // [2][200(j)][800(g)] f32
constexpr size_t OFF_WHHB = OFF_WHHP + (size_t)2*Hn*G4n;         // [2][200][800] bf16
constexpr size_t OFF_BSUM = OFF_WHHB + (size_t)2*Hn*G4n/2;       // [2][800]
constexpr size_t OFF_GB   = OFF_BSUM + (size_t)2*G4n;            // 2 slots x [2][64][64][800] bf16
constexpr size_t OFF_HCAT = OFF_GB + (size_t)2*2*Bn*TCn*G4n/2;   // [64][512][400] f32
constexpr size_t OFF_E    = OFF_HCAT + (size_t)Bn*Tn*2*Hn;       // [64][512][25]
constexpr size_t OFF_HST  = OFF_E + (size_t)Bn*Tn*Ln;            // [2][64][200]
constexpr size_t OFF_CST  = OFF_HST + (size_t)2*Bn*Hn;           // [2][64][200]
constexpr size_t OFF_PART = OFF_CST + (size_t)2*Bn*Hn;           // [64]

#define SMEM_BYTES 153664   // rec: 136000+16000+1664; gemm: 4x13056 (union)

__device__ __forceinline__ float sigf(float x) { return 1.0f / (1.0f + expf(-x)); }
__device__ __forceinline__ float rdlane(float v, int j) {
    return __uint_as_float(__builtin_amdgcn_readlane(__float_as_uint(v), j));
}

// ---------------- prep: transpose/pack weights (fp32 + bf16), zero state ----------------
__global__ void prep_kernel(const float* __restrict__ Wih_f, const float* __restrict__ Whh_f,
                            const float* __restrict__ bih_f, const float* __restrict__ bhh_f,
                            const float* __restrict__ Wih_b, const float* __restrict__ Whh_b,
                            const float* __restrict__ bih_b, const float* __restrict__ bhh_b,
                            float* __restrict__ ws) {
    int tid = blockIdx.x * blockDim.x + threadIdx.x;
    int nth = gridDim.x * blockDim.x;
    float* WihT = ws + OFF_WIHT;
    float* WhhP = ws + OFF_WHHP;
    unsigned short* WhhB = (unsigned short*)(ws + OFF_WHHB);
    float* bsum = ws + OFF_BSUM;
    float* hst  = ws + OFF_HST;
    float* cst  = ws + OFF_CST;
    for (int i = tid; i < 2*Dn*NPADn; i += nth) {
        int d = i / (Dn*NPADn); int r = i % (Dn*NPADn); int k = r / NPADn; int g = r % NPADn;
        const float* W = d ? Wih_b : Wih_f;
        WihT[i] = (g < G4n) ? W[(size_t)g*Dn + k] : 0.0f;
    }
    for (int i = tid; i < 2*Hn*G4n; i += nth) {   // [d][j][k*4+q] = Whh[q*H+k][j]
        int d = i / (Hn*G4n); int r = i % (Hn*G4n);
        int j = r / G4n; int g = r % G4n;
        int k = g >> 2, q = g & 3;
        const float* W = d ? Whh_b : Whh_f;
        float v = W[(size_t)(q*Hn + k)*Hn + j];
        WhhP[i] = v;
        WhhB[i] = (unsigned short)(__float_as_uint(v) >> 16);   // bf16 truncate
    }
    for (int i = tid; i < 2*G4n; i += nth) {
        int d = i / G4n; int g = i % G4n;
        bsum[i] = d ? (bih_b[g] + bhh_b[g]) : (bih_f[g] + bhh_f[g]);
    }
    for (int i = tid; i < 2*Bn*Hn; i += nth) { hst[i] = 0.0f; cst[i] = 0.0f; }
}

// ---------------- gemm role: one 256-thread quarter computes one (g-tile, b-pair, dir) tile ----------------
__device__ __forceinline__ void gemm_role(const float* __restrict__ X, float* __restrict__ ws,
                                          int chunk, int tile, int tid, char* smem) {
    const float* WihT = ws + OFF_WIHT;
    const float* bsum = ws + OFF_BSUM;
    unsigned short* Gb = (unsigned short*)(ws + OFF_GB) + (size_t)(chunk & 1) * 2 * Bn * TCn * G4n;
    int q4 = tid >> 8;
    int t2 = tid & 255;
    float* As = (float*)(smem + q4 * 13056);        // [16][136]
    float* Bs = As + 16 * 136;                      // [16][68]
    int g0i = tile % 13; int rem = tile / 13;
    int bp = rem % 32;   int d = rem / 32;
    int g0 = g0i * 64;
    int tx = t2 % 16, ty = t2 / 16;
    int t_base = (d == 0) ? chunk * TCn : (Tn - (chunk + 1) * TCn);
    const float* Bmat = WihT + (size_t)d * Dn * NPADn;

    float acc[8][4] = {{0.f}};
    int lr = t2 / 2, lk = t2 % 2;
    int bk = t2 / 16, bg = t2 % 16;
    int a_b = bp * 2 + lr / 64;
    int a_t = t_base + (lr % 64);
    const float* Arow = X + ((size_t)a_b * Tn + a_t) * Dn;

    for (int kt = 0; kt < Dn; kt += 16) {
        float4 a4a = *(const float4*)(Arow + kt + lk * 8);
        float4 a4b = *(const float4*)(Arow + kt + lk * 8 + 4);
        float4 b4  = *(const float4*)(Bmat + (size_t)(kt + bk) * NPADn + g0 + bg * 4);
        __syncthreads();
        As[(lk*8+0)*136 + lr] = a4a.x; As[(lk*8+1)*136 + lr] = a4a.y;
        As[(lk*8+2)*136 + lr] = a4a.z; As[(lk*8+3)*136 + lr] = a4a.w;
        As[(lk*8+4)*136 + lr] = a4b.x; As[(lk*8+5)*136 + lr] = a4b.y;
        As[(lk*8+6)*136 + lr] = a4b.z; As[(lk*8+7)*136 + lr] = a4b.w;
        *(float4*)&Bs[bk*68 + bg*4] = b4;
        __syncthreads();
        #pragma unroll
        for (int kk = 0; kk < 16; ++kk) {
            float4 af0 = *(const float4*)&As[kk*136 + ty*8];
            float4 af1 = *(const float4*)&As[kk*136 + ty*8 + 4];
            float4 bf  = *(const float4*)&Bs[kk*68 + tx*4];
            acc[0][0] += af0.x*bf.x; acc[0][1] += af0.x*bf.y; acc[0][2] += af0.x*bf.z; acc[0][3] += af0.x*bf.w;
            acc[1][0] += af0.y*bf.x; acc[1][1] += af0.y*bf.y; acc[1][2] += af0.y*bf.z; acc[1][3] += af0.y*bf.w;
            acc[2][0] += af0.z*bf.x; acc[2][1] += af0.z*bf.y; acc[2][2] += af0.z*bf.z; acc[2][3] += af0.z*bf.w;
            acc[3][0] += af0.w*bf.x; acc[3][1] += af0.w*bf.y; acc[3][2] += af0.w*bf.z; acc[3][3] += af0.w*bf.w;
            acc[4][0] += af1.x*bf.x; acc[4][1] += af1.x*bf.y; acc[4][2] += af1.x*bf.z; acc[4][3] += af1.x*bf.w;
            acc[5][0] += af1.y*bf.x; acc[5][1] += af1.y*bf.y; acc[5][2] += af1.y*bf.z; acc[5][3] += af1.y*bf.w;
            acc[6][0] += af1.z*bf.x; acc[6][1] += af1.z*bf.y; acc[6][2] += af1.z*bf.z; acc[6][3] += af1.z*bf.w;
            acc[7][0] += af1.w*bf.x; acc[7][1] += af1.w*bf.y; acc[7][2] += af1.w*bf.z; acc[7][3] += af1.w*bf.w;
        }
    }
    #pragma unroll
    for (int ii = 0; ii < 8; ++ii) {
        int r = ty * 8 + ii;
        int b = bp * 2 + r / 64;
        int tloc = r % 64;
        #pragma unroll
        for (int jj = 0; jj < 4; ++jj) {
            int g = g0 + tx * 4 + jj;
            if (g < G4n) {
                int k = g % Hn, q = g / Hn;
                float v = acc[ii][jj] + bsum[d*G4n + g];
                Gb[(((size_t)d*Bn + b)*TCn + tloc)*G4n + k*4 + q] =
                    (unsigned short)(__float_as_uint(v) >> 16);
            }
        }
    }
}

// ---------------- rec role: 3-tier Whh (fp32-VGPR / bf16-LDS / bf16-L1-stream) ----------------
__device__ __forceinline__ void rec_role(const float* __restrict__ mask, float* __restrict__ ws,
                                         int chunk, int b, int d, int tid, char* smem) {
    const unsigned short* Gbs = (const unsigned short*)(ws + OFF_GB) + (size_t)(chunk & 1) * 2 * Bn * TCn * G4n;
    float* Hcat = ws + OFF_HCAT;
    float* hst = ws + OFF_HST;
    float* cst = ws + OFF_CST;
    const float* WP = ws + OFF_WHHP;
    const unsigned short* WBbase = (const unsigned short*)(ws + OFF_WHHB);

    uint2*  wldsB   = (uint2*)smem;                  // [JLB][1000]  136000 B
    float4* partial = (float4*)(smem + 136000);      // [5][200]     16000 B
    float*  hbuf    = (float*)(smem + 152000);       // [2][208]     1664 B

    int k = tid % 200;
    int part = tid / 200;          // 0..5 (part 5: 24 idle threads)
    bool act = (part < 5);
    int cbase = (act ? part : 0) * 40;
    int qq = tid & 3, kk = tid >> 2;
    bool bact = (tid < 800);

    const float* Wd = WP + (size_t)d * Hn * G4n;
    const unsigned short* WB = WBbase + (size_t)d * Hn * G4n;
    #define LW(i) float4 w##i = *(const float4*)(Wd + (size_t)(cbase + i) * G4n + k * 4);
    LW(0) LW(1) LW(2) LW(3) LW(4) LW(5) LW(6) LW(7) LW(8) LW(9)
    LW(10) LW(11) LW(12) LW(13) LW(14) LW(15) LW(16) LW(17) LW(18) LW(19)
    #undef LW
    int lbase = (act ? part : 0) * 200 + k;
    if (act) {
        #pragma unroll
        for (int jj = 0; jj < JLB; ++jj)
            wldsB[jj * 1000 + part * 200 + k] = *(const uint2*)(WB + (size_t)(cbase + JV + jj) * G4n + k * 4);
    }
    size_t soff = ((size_t)d * Bn + b) * Hn;
    float hr = 0.f, cr = 0.f;
    if (bact && qq == 0) {
        hr = hst[soff + kk];
        cr = cst[soff + kk];
    }
    if (tid < 200) hbuf[tid] = hst[soff + tid];
    __syncthreads();

    const unsigned short* WstB = WB + (size_t)(cbase + JV + JLB) * G4n + k * 4;
    const unsigned short* GbRow = Gbs + ((size_t)d * Bn + b) * TCn * G4n;
    const float* mrow = mask + (size_t)b * Tn;
    float* Hrow = Hcat + (size_t)b * Tn * (2 * Hn) + d * Hn;

    #define FMAB(U, H) { \
        float bx = __uint_as_float((U).x << 16); \
        float by = __uint_as_float((U).x & 0xffff0000u); \
        float bz = __uint_as_float((U).y << 16); \
        float bw = __uint_as_float((U).y & 0xffff0000u); \
        acc.x += bx*(H); acc.y += by*(H); acc.z += bz*(H); acc.w += bw*(H); }
    #define FMA1(W, H) acc.x += (W).x*(H); acc.y += (W).y*(H); acc.z += (W).z*(H); acc.w += (W).w*(H);

    int cur = 0;
    for (int s = 0; s < TCn; ++s) {
        int tg, tloc;
        if (d == 0) { tloc = s; tg = chunk * TCn + s; }
        else        { tloc = TCn - 1 - s; tg = Tn - 1 - (chunk * TCn + s); }
        // deferred coalesced Hcat store of previous step's h
        if (s > 0 && tid < 200) {
            int tgp = (d == 0) ? (chunk * TCn + s - 1) : (Tn - 1 - (chunk * TCn + s - 1));
            Hrow[(size_t)tgp * (2 * Hn) + tid] = hbuf[cur * 208 + tid];
        }
        // phase-B prefetch: gate-input (bf16) + mask
        float m_ = 0.f, gq = 0.f;
        if (bact) {
            m_ = mrow[tg];
            unsigned short gub = GbRow[(size_t)tloc * G4n + tid];
            gq = __uint_as_float((unsigned int)gub << 16);
        }
        // ---- Phase A ----
        {
            uint2 t0 = *(const uint2*)(WstB + (size_t)0 * G4n);
            uint2 t1 = *(const uint2*)(WstB + (size_t)1 * G4n);
            uint2 t2s = *(const uint2*)(WstB + (size_t)2 * G4n);
            float4 acc = {0.f, 0.f, 0.f, 0.f};
            float4 hv;
            const float* hb = hbuf + cur * 208;
            hv = *(const float4*)&hb[cbase + 0];
            FMA1(w0, hv.x) FMA1(w1, hv.y) FMA1(w2, hv.z) FMA1(w3, hv.w)
            hv = *(const float4*)&hb[cbase + 4];
            FMA1(w4, hv.x) FMA1(w5, hv.y) FMA1(w6, hv.z) FMA1(w7, hv.w)
            hv = *(const float4*)&hb[cbase + 8];
            FMA1(w8, hv.x) FMA1(w9, hv.y) FMA1(w10, hv.z) FMA1(w11, hv.w)
            hv = *(const float4*)&hb[cbase + 12];
            FMA1(w12, hv.x) FMA1(w13, hv.y) FMA1(w14, hv.z) FMA1(w15, hv.w)
            hv = *(const float4*)&hb[cbase + 16];
            FMA1(w16, hv.x) FMA1(w17, hv.y) FMA1(w18, hv.z) FMA1(w19, hv.w)
            {
                uint2 u0 = wldsB[0*1000+lbase], u1 = wldsB[1*1000+lbase];
                uint2 u2 = wldsB[2*1000+lbase], u3 = wldsB[3*1000+lbase];
                hv = *(const float4*)&hb[cbase + 20];
                FMAB(u0, hv.x) FMAB(u1, hv.y) FMAB(u2, hv.z) FMAB(u3, hv.w)
            }
            {
                uint2 u0 = wldsB[4*1000+lbase], u1 = wldsB[5*1000+lbase];
                uint2 u2 = wldsB[6*1000+lbase], u3 = wldsB[7*1000+lbase];
                hv = *(const float4*)&hb[cbase + 24];
                FMAB(u0, hv.x) FMAB(u1, hv.y) FMAB(u2, hv.z) FMAB(u3, hv.w)
            }
            {
                uint2 u0 = wldsB[8*1000+lbase], u1 = wldsB[9*1000+lbase];
                uint2 u2 = wldsB[10*1000+lbase], u3 = wldsB[11*1000+lbase];
                hv = *(const float4*)&hb[cbase + 28];
                FMAB(u0, hv.x) FMAB(u1, hv.y) FMAB(u2, hv.z) FMAB(u3, hv.w)
            }
            {
                uint2 u0 = wldsB[12*1000+lbase], u1 = wldsB[13*1000+lbase];
                uint2 u2 = wldsB[14*1000+lbase], u3 = wldsB[15*1000+lbase];
                hv = *(const float4*)&hb[cbase + 32];
                FMAB(u0, hv.x) FMAB(u1, hv.y) FMAB(u2, hv.z) FMAB(u3, hv.w)
            }
            {
                uint2 u16 = wldsB[16*1000+lbase];
                hv = *(const float4*)&hb[cbase + 36];
                FMAB(u16, hv.x) FMAB(t0, hv.y) FMAB(t1, hv.z) FMAB(t2s, hv.w)
            }
            if (act) partial[part * 200 + k] = acc;
        }
        __syncthreads();
        // ---- Phase B ----
        if (bact) {
            const float* pf = (const float*)partial;
            float g = gq + (((pf[0*800 + tid] + pf[1*800 + tid]) +
                             (pf[2*800 + tid] + pf[3*800 + tid])) + pf[4*800 + tid]);
            float arg = (qq == 2) ? 2.f * g : g;
            float sg = 1.f / (1.f + expf(-arg));
            float a = (qq == 2) ? 2.f * sg - 1.f : sg;   // tanh(g) = 2*sig(2g)-1
            float x1 = __shfl_xor(a, 1);
            float x2 = __shfl_xor(a, 2);
            float x3 = __shfl_xor(x1, 2);
            if (qq == 0) {
                float i_ = a, f_ = x1, gg_ = x2, o_ = x3;
                float cn = f_ * cr + i_ * gg_;
                float hn = o_ * tanhf(cn);
                cr = m_ * cn + (1.f - m_) * cr;
                hr = m_ * hn + (1.f - m_) * hr;
                hbuf[(cur ^ 1) * 208 + kk] = hr;
            }
        }
        __syncthreads();
        cur ^= 1;
    }
    #undef FMAB
    #undef FMA1
    if (tid < 200) {
        int tgp = (d == 0) ? (chunk * TCn + TCn - 1) : (Tn - 1 - (chunk * TCn + TCn - 1));
        Hrow[(size_t)tgp * (2 * Hn) + tid] = hbuf[cur * 208 + tid];
    }
    if (bact && qq == 0) {
        hst[soff + kk] = hr;
        cst[soff + kk] = cr;
    }
}

// ---------------- fused launch: blocks [0,nrec) = rec(rec_chunk); rest = gemm(gemm_chunk) ----------------
__global__ __launch_bounds__(1024, 4) void fused_kernel(const float* __restrict__ X,
                                                        const float* __restrict__ mask,
                                                        float* __restrict__ ws,
                                                        int rec_chunk, int gemm_chunk, int nrec) {
    __shared__ __align__(16) char smem[SMEM_BYTES];
    int bx = blockIdx.x;
    int tid = threadIdx.x;
    if (bx < nrec) {
        rec_role(mask, ws, rec_chunk, bx & 63, bx >> 6, tid, smem);
    } else {
        int tile = (bx - nrec) * 4 + (tid >> 8);
        gemm_role(X, ws, gemm_chunk, tile, tid, smem);
    }
}

// ---------------- emissions: E = (Hcat @ Wl^T + bl) * mask ----------------
__global__ __launch_bounds__(256) void emis_kernel(const float* __restrict__ mask,
                                                   const float* __restrict__ Wl,
                                                   const float* __restrict__ bl,
                                                   float* __restrict__ ws) {
    const float* Hcat = ws + OFF_HCAT;
    float* E = ws + OFF_E;
    __shared__ float Wls[Ln * 404];
    __shared__ float Hs[16 * 404];
    int tid = threadIdx.x;
    for (int i = tid; i < Ln * 100; i += 256) {
        int l = i / 100, k4 = i % 100;
        *(float4*)&Wls[l*404 + k4*4] = *(const float4*)(Wl + (size_t)l*Dn + k4*4);
    }
    int rbase = blockIdx.x * 128;
    for (int sub = 0; sub < 8; ++sub) {
        int r0 = rbase + sub * 16;
        __syncthreads();
        for (int i = tid; i < 16 * 100; i += 256) {
            int r = i / 100, k4 = i % 100;
            *(float4*)&Hs[r*404 + k4*4] = *(const float4*)(Hcat + (size_t)(r0 + r)*Dn + k4*4);
        }
        __syncthreads();
        for (int o = tid; o < 16 * Ln; o += 256) {
            int r = o / Ln, l = o % Ln;
            float acc = 0.f;
            #pragma unroll 4
            for (int k4 = 0; k4 < 100; ++k4) {
                float4 h = *(const float4*)&Hs[r*404 + k4*4];
                float4 wv = *(const float4*)&Wls[l*404 + k4*4];
                acc += h.x*wv.x + h.y*wv.y + h.z*wv.z + h.w*wv.w;
            }
            int row = r0 + r;            // row == b*T + t
            float m = mask[row];
            E[(size_t)row * Ln + l] = (acc + bl[l]) * m;
        }
    }
}

// ---------------- fused CRF + Viterbi: 64 blocks x 128 threads (wave0=CRF, wave1=Viterbi) ----------------
// alpha/delta live in lane registers; broadcast via readlane (no LDS round-trip, no scan barriers).
__global__ __launch_bounds__(128) void decode_kernel(const float* __restrict__ mask,
                                                     const int* __restrict__ labels,
                                                     const float* __restrict__ trans,
                                                     const float* __restrict__ start,
                                                     const float* __restrict__ endv,
                                                     float* __restrict__ ws,
                                                     float* __restrict__ out) {
    int b = blockIdx.x;
    int tid = threadIdx.x;
    int wvid = tid >> 6;
    int l = tid & 63;
    const float* E = ws + OFF_E;
    float* part = ws + OFF_PART;

    __shared__ __align__(16) float Es[Tn * Ln];
    __shared__ float trs[Ln * Ln];
    __shared__ unsigned char ptrs[Tn][Ln];
    __shared__ unsigned char ys[Tn];

    {
        const float4* src = (const float4*)(E + (size_t)b * Tn * Ln);
        float4* dst = (float4*)Es;
        for (int i = tid; i < Tn * Ln / 4; i += 128) dst[i] = src[i];
        for (int i = tid; i < Ln * Ln; i += 128) trs[i] = trans[i];
    }
    float cnt = 0.f;
    for (int t = l; t < Tn; t += 64) cnt += mask[(size_t)b * Tn + t];
    for (int off = 32; off; off >>= 1) cnt += __shfl_xor(cnt, off);
    int len = (int)(cnt + 0.5f);
    float trc[Ln];
    #pragma unroll
    for (int j = 0; j < Ln; ++j) trc[j] = -1e30f;
    if (l < Ln) {
        #pragma unroll
        for (int j = 0; j < Ln; ++j) trc[j] = trans[j * Ln + l];
    }
    __syncthreads();

    if (wvid == 0) {
        float alpha = (l < Ln) ? start[l] + Es[l] : -1e30f;
        for (int t = 1; t < len; ++t) {
            float v[Ln];
            #pragma unroll
            for (int j = 0; j < Ln; ++j) v[j] = rdlane(alpha, j) + trc[j];
            float r[12];
            #pragma unroll
            for (int j = 0; j < 12; ++j) r[j] = fmaxf(v[j], v[j + 12]);
            r[0] = fmaxf(r[0], v[24]);
            #pragma unroll
            for (int j = 0; j < 6; ++j) r[j] = fmaxf(r[j], r[j + 6]);
            #pragma unroll
            for (int j = 0; j < 3; ++j) r[j] = fmaxf(r[j], r[j + 3]);
            float mx = fmaxf(fmaxf(r[0], r[1]), r[2]);
            float e[Ln];
            #pragma unroll
            for (int j = 0; j < Ln; ++j) e[j] = __expf(v[j] - mx);
            #pragma unroll
            for (int j = 0; j < 12; ++j) e[j] += e[j + 12];
            e[0] += e[24];
            #pragma unroll
            for (int j = 0; j < 6; ++j) e[j] += e[j + 6];
            #pragma unroll
            for (int j = 0; j < 3; ++j) e[j] += e[j + 3];
            float s = (e[0] + e[1]) + e[2];
            float nv = mx + __logf(s) + Es[t * Ln + l];
            alpha = (l < Ln) ? nv : -1e30f;
        }
        float vfin = (l < Ln) ? alpha + endv[l] : -1e30f;
        float mxf = vfin;
        for (int off = 32; off; off >>= 1) mxf = fmaxf(mxf, __shfl_xor(mxf, off));
        float sf = (l < Ln) ? __expf(vfin - mxf) : 0.f;
        for (int off = 32; off; off >>= 1) sf += __shfl_xor(sf, off);
        float logZ = mxf + __logf(sf);
        float psum = 0.f;
        for (int t = l; t < len; t += 64) {
            if (t >= 1) {
                int lt = labels[(size_t)b * Tn + t];
                int lp = labels[(size_t)b * Tn + t - 1];
                psum += Es[t * Ln + lt] + trs[lp * Ln + lt];
            }
        }
        for (int off = 32; off; off >>= 1) psum += __shfl_xor(psum, off);
        if (l == 0) {
            int l0 = labels[(size_t)b * Tn];
            int yl = labels[(size_t)b * Tn + len - 1];
            part[b] = start[l0] + Es[l0] + psum + endv[yl] - logZ;
        }
    } else {
        float delta = (l < Ln) ? start[l] + Es[l] : -1e30f;
        for (int t = 1; t < len; ++t) {
            float best = -1e30f; int ba = 0;
            #pragma unroll
            for (int j = 0; j < Ln; ++j) {
                float c = rdlane(delta, j) + trc[j];
                if (c > best) { best = c; ba = j; }   // strict >: first-max (jnp.argmax)
            }
            float nd = best + Es[t * Ln + l];
            if (l < Ln) ptrs[t][l] = (unsigned char)ba;
            delta = (l < Ln) ? nd : -1e30f;
        }
        float bb = -1e30f; int y = 0;
        #pragma unroll
        for (int j = 0; j < Ln; ++j) {
            float c = rdlane(delta, j) + endv[j];
            if (c > bb) { bb = c; y = j; }
        }
        if (l == 0) {
            ys[len - 1] = (unsigned char)y;
            int yy = y;
            for (int t = len - 1; t >= 1; --t) { yy = ptrs[t][yy]; ys[t - 1] = (unsigned char)yy; }
        }
        for (int t = l; t < Tn; t += 64) {
            out[1 + (size_t)b * Tn + t] = (t < len) ? (float)ys[t] : 0.f;
        }
    }
}

// ---------------- finalize loss ----------------
__global__ __launch_bounds__(64) void fin_kernel(float* __restrict__ ws, float* __restrict__ out) {
    const float* part = ws + OFF_PART;
    int l = threadIdx.x;
    float v = (l < Bn) ? part[l] : 0.f;
    for (int off = 32; off; off >>= 1) v += __shfl_xor(v, off);
    if (l == 0) out[0] = -v / (float)Bn;
}

extern "C" void kernel_launch(void* const* d_in, const int* in_sizes, int n_in,
                              void* d_out, int out_size, void* d_ws, size_t ws_size,
                              hipStream_t stream) {
    (void)in_sizes; (void)n_in; (void)out_size; (void)ws_size;
    const float* X      = (const float*)d_in[0];
    const float* mask   = (const float*)d_in[1];
    const int*   labels = (const int*)d_in[2];
    const float* Wih_f  = (const float*)d_in[3];
    const float* Whh_f  = (const float*)d_in[4];
    const float* bih_f  = (const float*)d_in[5];
    const float* bhh_f  = (const float*)d_in[6];
    const float* Wih_b  = (const float*)d_in[7];
    const float* Whh_b  = (const float*)d_in[8];
    const float* bih_b  = (const float*)d_in[9];
    const float* bhh_b  = (const float*)d_in[10];
    const float* Wl     = (const float*)d_in[11];
    const float* bl     = (const float*)d_in[12];
    const float* trans  = (const float*)d_in[13];
    const float* start  = (const float*)d_in[14];
    const float* endv   = (const float*)d_in[15];
    float* ws  = (float*)d_ws;
    float* out = (float*)d_out;

    prep_kernel<<<128, 256, 0, stream>>>(Wih_f, Whh_f, bih_f, bhh_f,
                                         Wih_b, Whh_b, bih_b, bhh_b, ws);
    // L0: gemm chunk 0 only (208 blocks x 4 quarter-tiles = 832 tiles)
    fused_kernel<<<208, 1024, 0, stream>>>(X, mask, ws, 0, 0, 0);
    // L1..L7: rec(c-1) overlapped with gemm(c)
    for (int c = 1; c < NCH; ++c)
        fused_kernel<<<336, 1024, 0, stream>>>(X, mask, ws, c - 1, c, 128);
    // L8: rec chunk 7 only
    fused_kernel<<<128, 1024, 0, stream>>>(X, mask, ws, NCH - 1, 0, 128);
    emis_kernel<<<256, 256, 0, stream>>>(mask, Wl, bl, ws);
    decode_kernel<<<64, 128, 0, stream>>>(mask, labels, trans, start, endv, ws, out);
    fin_kernel<<<1, 64, 0, stream>>>(ws, out);
}